// Round 8
// baseline (1834.106 us; speedup 1.0000x reference)
//
#include <hip/hip_runtime.h>
#include <math.h>

typedef __bf16 bf16x8 __attribute__((ext_vector_type(8)));
typedef float  f32x16 __attribute__((ext_vector_type(16)));

static __device__ __forceinline__ f32x16 MFMA(bf16x8 a, bf16x8 b, f32x16 c){
  return __builtin_amdgcn_mfma_f32_32x32x16_bf16(a, b, c, 0, 0, 0);
}
static __device__ __forceinline__ unsigned short f2bf(float x){
  unsigned int u = __builtin_bit_cast(unsigned int, x);
  u += 0x7fffu + ((u >> 16) & 1u);   // RNE
  return (unsigned short)(u >> 16);
}
static __device__ __forceinline__ unsigned int pack2(float a, float b){
  return ((unsigned int)f2bf(b) << 16) | (unsigned int)f2bf(a);
}
static __device__ __forceinline__ bf16x8 ldfrag(const unsigned short* p){
  return __builtin_bit_cast(bf16x8, *(const uint4*)p);
}
// C-layout row for 32x32x16: row = (reg&3) + 8*(reg>>2) + 4*(lane>>5)
static __device__ __forceinline__ int rowmap(int reg, int lane){
  return (reg & 3) + 8 * (reg >> 2) + 4 * (lane >> 5);
}

// ------------------------------------------------ weight transpose+cast (once)
__global__ __launch_bounds__(256) void k_wprep(const float* __restrict__ in_w,
    const float* __restrict__ q_w, const float* __restrict__ k_w,
    const float* __restrict__ v_w, unsigned short* __restrict__ wT){
  int idx = blockIdx.x * 256 + threadIdx.x;   // 983040 total
  float v;
  if (idx < 98304){
    int c = idx / 384, k = idx % 384;
    v = in_w[k * 256 + c];
  } else {
    int e = idx - 98304;
    int m = e / 73728, r = e % 73728;
    int c = r / 288, k = r % 288;
    int p = m % 3, layer = m / 3;
    const float* src = (p == 0) ? q_w : (p == 1) ? k_w : v_w;
    v = src[(size_t)layer * 73728 + k * 256 + c];
  }
  wT[idx] = f2bf(v);
}

// ------------------------------------------------ temporal emb (bf16, masked)
__global__ __launch_bounds__(256) void k_temporal(const float* __restrict__ tim,
                                                  unsigned int* __restrict__ tem){
  int idx = blockIdx.x * 256 + threadIdx.x;   // 65536*16
  int i = idx & 15, m = idx >> 4;
  float t = tim[m];
  float np = (t > 0.0f) ? 1.0f : 0.0f;
  float dv = expf((float)(2 * i) * (-0.28782313662425576f));
  float arg = t * dv;
  tem[m * 16 + i] = pack2(sinf(arg) * np, cosf(arg) * np);
}

// ------------------------------------------------ input projection (MFMA)
__global__ __launch_bounds__(256, 2) void k_inproj(const int* __restrict__ subj,
    const int* __restrict__ obj, const int* __restrict__ rel,
    const float* __restrict__ ent, const float* __restrict__ rele,
    const unsigned short* __restrict__ inwT, const float* __restrict__ in_b,
    unsigned short* __restrict__ enc){
  __shared__ __align__(16) unsigned short A[64 * 392];  // reused as SB[64*264] after
  int t = threadIdx.x;
  int m0 = blockIdx.x * 64;
  { // gather 64 rows of concat(ent[s],ent[o],rel[r]) as bf16
    int r = t >> 2, c = t & 3;
    int m = m0 + r;
    const float4* s0 = (const float4*)(ent  + (size_t)subj[m] * 128 + c * 32);
    const float4* s1 = (const float4*)(ent  + (size_t)obj[m]  * 128 + c * 32);
    const float4* s2 = (const float4*)(rele + (size_t)rel[m]  * 128 + c * 32);
    unsigned int* dst = (unsigned int*)&A[r * 392];
#pragma unroll
    for (int j = 0; j < 8; j++){
      float4 f0 = s0[j], f1 = s1[j], f2 = s2[j];
      dst[c * 16 + 2 * j]           = pack2(f0.x, f0.y);
      dst[c * 16 + 2 * j + 1]       = pack2(f0.z, f0.w);
      dst[64 + c * 16 + 2 * j]      = pack2(f1.x, f1.y);
      dst[64 + c * 16 + 2 * j + 1]  = pack2(f1.z, f1.w);
      dst[128 + c * 16 + 2 * j]     = pack2(f2.x, f2.y);
      dst[128 + c * 16 + 2 * j + 1] = pack2(f2.z, f2.w);
    }
  }
  __syncthreads();
  int w = t >> 6, lane = t & 63;
  int lrow = lane & 31, khalf = (lane >> 5) * 8;
  int colA = (w * 2) * 32 + lrow, colB = colA + 32;
  f32x16 acc[2][2] = {};
  bf16x8 pb0 = ldfrag(&inwT[(size_t)colA * 384 + khalf]);
  bf16x8 pb1 = ldfrag(&inwT[(size_t)colB * 384 + khalf]);
  for (int ks = 0; ks < 24; ks++){
    int koff = ks * 16 + khalf;
    bf16x8 a0 = ldfrag(&A[lrow * 392 + koff]);
    bf16x8 a1 = ldfrag(&A[(32 + lrow) * 392 + koff]);
    bf16x8 b0 = pb0, b1 = pb1;
    if (ks < 23){
      pb0 = ldfrag(&inwT[(size_t)colA * 384 + koff + 16]);
      pb1 = ldfrag(&inwT[(size_t)colB * 384 + koff + 16]);
    }
    acc[0][0] = MFMA(a0, b0, acc[0][0]);
    acc[1][0] = MFMA(a1, b0, acc[1][0]);
    acc[0][1] = MFMA(a0, b1, acc[0][1]);
    acc[1][1] = MFMA(a1, b1, acc[1][1]);
  }
  float bs0 = in_b[colA], bs1 = in_b[colB];
  __syncthreads();            // A dead; reuse as SB[64][264]
#pragma unroll
  for (int rt = 0; rt < 2; rt++)
#pragma unroll
    for (int reg = 0; reg < 16; reg++){
      int row = rt * 32 + rowmap(reg, lane);
      A[row * 264 + colA] = f2bf(acc[rt][0][reg] + bs0);
      A[row * 264 + colB] = f2bf(acc[rt][1][reg] + bs1);
    }
  __syncthreads();
  {
    int r = t >> 2, s = t & 3;
    const uint4* src = (const uint4*)&A[r * 264 + s * 64];
    uint4* dst = (uint4*)(enc + ((size_t)m0 + r) * 256 + s * 64);
#pragma unroll
    for (int j = 0; j < 8; j++) dst[j] = src[j];
  }
}

// ------------------------------------------------ Q,K,V projections (MFMA) v2
// 32-row blocks (8/nn): LDS 39.4 KB -> 4 blocks/CU, pass-1 accums 64 VGPR ->
// launch_bounds(256,4) -> 16 waves/CU (2x R7). 2-deep weight prefetch with
// FULLY UNROLLED k-loop (static ks&1 index — R4's rolled-loop dynamic index
// caused scratch demotion; unroll makes it register rotation).
__global__ __launch_bounds__(256, 4) void k_qkv(const unsigned short* __restrict__ enc,
    const float* __restrict__ cur, const unsigned short* __restrict__ tem,
    const unsigned short* __restrict__ wq, const unsigned short* __restrict__ wk,
    const unsigned short* __restrict__ wv, const float* __restrict__ bq,
    const float* __restrict__ bk, const float* __restrict__ bv,
    int nbase, int lzero,
    unsigned short* __restrict__ qb, unsigned short* __restrict__ kb,
    unsigned short* __restrict__ vtb){
  __shared__ __align__(16) unsigned short A[32 * 296];      // 18,944 B
  __shared__ __align__(16) unsigned short SBVT[256 * 40];   // 20,480 B (SB or VT)
  int t = threadIdx.x;
  int nn = blockIdx.x >> 3;
  int n  = nbase + nn;
  int r0 = (blockIdx.x & 7) * 32;
  { // gather 32 ci rows -> bf16 LDS (stride 296); 8 threads per row
    int r = t >> 3, c8 = t & 7;
    int grow = r0 + r;
    unsigned short* dst = &A[r * 296];
    if (grow < 128){
      const uint4* s4 = (const uint4*)(enc + ((size_t)n * 128 + grow) * 256 + c8 * 32);
      uint4* d4 = (uint4*)(dst + c8 * 32);
#pragma unroll
      for (int j = 0; j < 4; j++) d4[j] = s4[j];
    } else if (!lzero){
      const float4* s4 = (const float4*)(cur + ((size_t)n * 128 + grow - 128) * 256 + c8 * 32);
      unsigned int* d = (unsigned int*)(dst + c8 * 32);
#pragma unroll
      for (int j = 0; j < 8; j++){
        float4 f = s4[j];
        d[2 * j]     = pack2(f.x, f.y);
        d[2 * j + 1] = pack2(f.z, f.w);
      }
    } else {
      uint4* d4 = (uint4*)(dst + c8 * 32);
      uint4 z = make_uint4(0, 0, 0, 0);
#pragma unroll
      for (int j = 0; j < 4; j++) d4[j] = z;
    }
    int jr = (grow < 128) ? grow : grow - 128;
    if (c8 < 4)
      ((uint4*)(dst + 256))[c8] = ((const uint4*)(tem + ((size_t)n * 128 + jr) * 32))[c8];
  }
  __syncthreads();
  int w = t >> 6, lane = t & 63;
  int lrow = lane & 31, khalf = (lane >> 5) * 8;
  int colA = w * 64 + lrow, colB = colA + 32;

  // store one 32-row C pair -> SB -> coalesced global
  auto store_rc = [&](f32x16& accA, f32x16& accB, const float* bias,
                      unsigned short* out){
    float bs0 = bias[colA], bs1 = bias[colB];
    __syncthreads();
#pragma unroll
    for (int reg = 0; reg < 16; reg++){
      int row = rowmap(reg, lane);
      SBVT[row * 264 + colA] = f2bf(accA[reg] + bs0);
      SBVT[row * 264 + colB] = f2bf(accB[reg] + bs1);
    }
    __syncthreads();
    int r = t >> 3, seg = t & 7;
    const uint4* src = (const uint4*)&SBVT[r * 264 + seg * 32];
    uint4* dst = (uint4*)(out + ((size_t)nn * 256 + r0 + r) * 256 + seg * 32);
#pragma unroll
    for (int j = 0; j < 4; j++) dst[j] = src[j];
  };

  // ---- pass 1: Q and K share A fragments (2-deep prefetch, unrolled) ----
  {
    f32x16 aq0 = {}, aq1 = {}, ak0 = {}, ak1 = {};
    bf16x8 pq0[2], pq1[2], pk0[2], pk1[2];
#pragma unroll
    for (int i = 0; i < 2; i++){
      pq0[i] = ldfrag(&wq[(size_t)colA * 288 + i * 16 + khalf]);
      pq1[i] = ldfrag(&wq[(size_t)colB * 288 + i * 16 + khalf]);
      pk0[i] = ldfrag(&wk[(size_t)colA * 288 + i * 16 + khalf]);
      pk1[i] = ldfrag(&wk[(size_t)colB * 288 + i * 16 + khalf]);
    }
#pragma unroll
    for (int ks = 0; ks < 18; ks++){
      int b = ks & 1;                       // static after full unroll
      int koff = ks * 16 + khalf;
      bf16x8 a0 = ldfrag(&A[lrow * 296 + koff]);
      bf16x8 q0 = pq0[b], q1 = pq1[b], k0 = pk0[b], k1 = pk1[b];
      if (ks < 16){
        int kn2 = (ks + 2) * 16 + khalf;
        pq0[b] = ldfrag(&wq[(size_t)colA * 288 + kn2]);
        pq1[b] = ldfrag(&wq[(size_t)colB * 288 + kn2]);
        pk0[b] = ldfrag(&wk[(size_t)colA * 288 + kn2]);
        pk1[b] = ldfrag(&wk[(size_t)colB * 288 + kn2]);
      }
      aq0 = MFMA(a0, q0, aq0);
      aq1 = MFMA(a0, q1, aq1);
      ak0 = MFMA(a0, k0, ak0);
      ak1 = MFMA(a0, k1, ak1);
    }
    store_rc(aq0, aq1, bq, qb);
    store_rc(ak0, ak1, bk, kb);
  }

  // ---- pass 2: V (transposed out via VT, 2-deep prefetch, unrolled) ----
  {
    f32x16 av0 = {}, av1 = {};
    bf16x8 pv0[2], pv1[2];
#pragma unroll
    for (int i = 0; i < 2; i++){
      pv0[i] = ldfrag(&wv[(size_t)colA * 288 + i * 16 + khalf]);
      pv1[i] = ldfrag(&wv[(size_t)colB * 288 + i * 16 + khalf]);
    }
#pragma unroll
    for (int ks = 0; ks < 18; ks++){
      int b = ks & 1;
      int koff = ks * 16 + khalf;
      bf16x8 a0 = ldfrag(&A[lrow * 296 + koff]);
      bf16x8 v0 = pv0[b], v1 = pv1[b];
      if (ks < 16){
        int kn2 = (ks + 2) * 16 + khalf;
        pv0[b] = ldfrag(&wv[(size_t)colA * 288 + kn2]);
        pv1[b] = ldfrag(&wv[(size_t)colB * 288 + kn2]);
      }
      av0 = MFMA(a0, v0, av0);
      av1 = MFMA(a0, v1, av1);
    }
    float bs0 = bv[colA], bs1 = bv[colB];
    __syncthreads();           // SB phase done; reuse as VT[256][40]
#pragma unroll
    for (int reg = 0; reg < 16; reg++){
      int kl = rowmap(reg, lane);   // key within tile
      SBVT[colA * 40 + kl] = f2bf(av0[reg] + bs0);
      SBVT[colB * 40 + kl] = f2bf(av1[reg] + bs1);
    }
    __syncthreads();
    { // thread t = d-row: 64 B contiguous to vtb[nn][d][r0..r0+31]
      const uint4* src = (const uint4*)&SBVT[t * 40];
      uint4* dst = (uint4*)(vtb + ((size_t)nn * 256 + t) * 256 + r0);
#pragma unroll
      for (int j = 0; j < 4; j++) dst[j] = src[j];
    }
  }
}

// ------------------------------------------------ attention v4 (R7, validated)
// v1 topology (2 blocks/nn) + structural tile skipping (ct<=w, +diag for cur
// waves; fm rows force full path -> uniform 1/256). PV fused per-tile via
// per-wave 32x40 LDS P buffer. FETCH ~1.3x structural (R7 measured).
__global__ __launch_bounds__(256, 2) void k_attn(const unsigned short* __restrict__ qb,
    const unsigned short* __restrict__ kb, const unsigned short* __restrict__ vtb,
    unsigned short* __restrict__ enc, float* __restrict__ cur,
    const float* __restrict__ tim, int nbase, int lzero, int hsel,
    float* __restrict__ feat){
  __shared__ __align__(16) unsigned short PB[4][32 * 40];  // 10,240 B
  __shared__ float TS[128];
  __shared__ unsigned long long MS[2];
  int t = threadIdx.x;
  int nn = blockIdx.x >> 1;
  int n  = nbase + nn;
  int q0 = (blockIdx.x & 1) * 128;
  int w = t >> 6, lane = t & 63;
  int lrow = lane & 31, kh8 = (lane >> 5) * 8;
  int qrow = q0 + w * 32;
  if (t < 128) TS[t] = tim[(size_t)n * 128 + t];
  __syncthreads();
  if (w == 0){
    unsigned long long m0 = __ballot(TS[lane] > 0.0f);
    unsigned long long m1 = __ballot(TS[64 + lane] > 0.0f);
    if (lane == 0){ MS[0] = m0; MS[1] = m1; }
  }
  __syncthreads();
  bool xw = (qrow < 128);   // wave-uniform
  unsigned int fmbits = 0;  // fully-masked enc rows -> uniform softmax
  if (xw){
    unsigned long long km0 = MS[0], km1 = MS[1];
#pragma unroll
    for (int reg = 0; reg < 16; reg++){
      int Q = qrow + rowmap(reg, lane);      // < 128; keys [0,Q) relevant
      unsigned long long a = (Q >= 64) ? km0 : (km0 & ((1ull << Q) - 1ull));
      int c = __popcll(a);
      if (Q > 64) c += __popcll(km1 & ((1ull << (Q - 64)) - 1ull));
      if (c == 0) fmbits |= 1u << reg;
    }
  }
  bool fmany = (__ballot(fmbits != 0) != 0ull);   // wave-uniform
  int diagct = xw ? -1 : 4 + w;
  const unsigned short* qn = qb  + (size_t)nn * 65536;
  const unsigned short* kn = kb  + (size_t)nn * 65536;
  const unsigned short* vn = vtb + (size_t)nn * 65536;
  unsigned short* myP = PB[w];
  // preload Q fragments (reused across all active tiles)
  bf16x8 qf[16];
#pragma unroll
  for (int ks = 0; ks < 16; ks++)
    qf[ks] = ldfrag(&qn[(size_t)(qrow + lrow) * 256 + ks * 16 + kh8]);

  float sumacc[16];
#pragma unroll
  for (int i = 0; i < 16; i++) sumacc[i] = 0.0f;
  f32x16 ov[8] = {};

#pragma unroll
  for (int ct = 0; ct < 8; ct++){
    bool active = fmany || (ct <= w) || (ct == diagct);  // wave-uniform
    if (!active) continue;
    // ---- scores for this 32-key tile ----
    f32x16 s = {};
#pragma unroll
    for (int ks = 0; ks < 16; ks++){
      bf16x8 b = ldfrag(&kn[(size_t)(ct * 32 + lrow) * 256 + ks * 16 + kh8]);
      s = MFMA(qf[ks], b, s);
    }
    int key = ct * 32 + lrow;
    bool keylo = (ct < 4);
    bool tzk = keylo ? (TS[key] == 0.0f) : false;
    // ---- mask + exp + P tile (per-wave LDS, stride 40) ----
#pragma unroll
    for (int reg = 0; reg < 16; reg++){
      int rl = rowmap(reg, lane);
      int Q = qrow + rl;
      bool masked;
      if (xw)  masked = (key >= Q) || !keylo || tzk;
      else {
        int qq = Q - 128;
        masked = keylo ? ((key >= qq) || tzk) : ((key - 128) != qq);
      }
      float e = ((fmbits >> reg) & 1u) ? 0.00390625f
               : (masked ? 0.0f : __expf(s[reg] * 0.0625f));
      sumacc[reg] += e;
      myP[rl * 40 + (key & 31)] = f2bf(e);
    }
    // ---- PV accumulate for this tile (C->A via per-wave LDS) ----
#pragma unroll
    for (int hs = 0; hs < 2; hs++){
      bf16x8 a = ldfrag(&myP[lrow * 40 + hs * 16 + kh8]);
#pragma unroll
      for (int dt = 0; dt < 8; dt++){
        bf16x8 b = ldfrag(&vn[(size_t)(dt * 32 + lrow) * 256 + ct * 32 + hs * 16 + kh8]);
        ov[dt] = MFMA(a, b, ov[dt]);
      }
    }
  }
  // row-sum reduce across the 32 key-lanes of each row
#pragma unroll
  for (int reg = 0; reg < 16; reg++){
    float sv = sumacc[reg];
#pragma unroll
    for (int mk = 1; mk <= 16; mk <<= 1) sv += __shfl_xor(sv, mk, 64);
    sumacc[reg] = 1.0f / sv;   // never 0: fm rows sum to 1; cur rows >=1 key
  }
  // ---- epilogue ----
#pragma unroll
  for (int reg = 0; reg < 16; reg++){
    int rl = rowmap(reg, lane);
    int Q = qrow + rl;
    float rs = sumacc[reg];
    if (xw){
      size_t base = ((size_t)n * 128 + Q) * 256;
#pragma unroll
      for (int dt = 0; dt < 8; dt++)
        enc[base + dt * 32 + lrow] = f2bf(ov[dt][reg] * rs);
    } else {
      int qq = Q - 128;
      float tq = TS[qq];
      size_t base = ((size_t)n * 128 + qq) * 256;
      bool wf = (hsel >= 0) && (qq == 127);
      if (lzero){
#pragma unroll
        for (int dt = 0; dt < 8; dt++){
          float x = ov[dt][reg] * rs;
          float ex = __expf(2.0f * x);
          float th = (tq > 0.0f) ? (1.0f - 2.0f / (ex + 1.0f)) : 0.0f;
          cur[base + dt * 32 + lrow] = th;
          if (wf) feat[(size_t)n * 512 + hsel * 256 + dt * 32 + lrow] = th;
        }
      } else {
#pragma unroll
        for (int dt = 0; dt < 8; dt++){
          float c = cur[base + dt * 32 + lrow];
          if (tq > 0.0f){
            float x = ov[dt][reg] * rs;
            float ex = __expf(2.0f * x);
            c += 1.0f - 2.0f / (ex + 1.0f);
            cur[base + dt * 32 + lrow] = c;
          }
          if (wf) feat[(size_t)n * 512 + hsel * 256 + dt * 32 + lrow] = c;
        }
      }
    }
  }
}

// ------------------------------------------------ output MLP head
__global__ __launch_bounds__(256) void k_mlp(const float* __restrict__ feat,
    const float* __restrict__ w1, const float* __restrict__ b1,
    const float* __restrict__ w2, const float* __restrict__ b2,
    float* __restrict__ out){
  __shared__ float F[512];
  __shared__ float red[4];
  int n = blockIdx.x, t = threadIdx.x;
  F[t]       = feat[(size_t)n * 512 + t];
  F[t + 256] = feat[(size_t)n * 512 + 256 + t];
  __syncthreads();
  float acc = 0.0f;
  for (int k4 = 0; k4 < 128; k4++){
    float b0v = w1[(k4 * 4 + 0) * 256 + t];
    float b1v = w1[(k4 * 4 + 1) * 256 + t];
    float b2v = w1[(k4 * 4 + 2) * 256 + t];
    float b3v = w1[(k4 * 4 + 3) * 256 + t];
    const float4 f = *(const float4*)&F[k4 * 4];
    acc = fmaf(f.x, b0v, fmaf(f.y, b1v, fmaf(f.z, b2v, fmaf(f.w, b3v, acc))));
  }
  acc += b1[t];
  float g = 0.5f * acc * (1.0f + erff(acc * 0.7071067811865475f));
  float part = g * w2[t];
#pragma unroll
  for (int mk = 1; mk < 64; mk <<= 1) part += __shfl_xor(part, mk, 64);
  if ((t & 63) == 0) red[t >> 6] = part;
  __syncthreads();
  if (t == 0) out[n] = red[0] + red[1] + red[2] + red[3] + b2[0];
}

// ------------------------------------------------ launch
extern "C" void kernel_launch(void* const* d_in, const int* in_sizes, int n_in,
                              void* d_out, int out_size, void* d_ws, size_t ws_size,
                              hipStream_t stream){
  const int*   subj = (const int*)  d_in[0];
  const int*   obj  = (const int*)  d_in[1];
  const int*   rel  = (const int*)  d_in[2];
  const float* tim  = (const float*)d_in[3];
  const float* ent  = (const float*)d_in[4];
  const float* rele = (const float*)d_in[5];
  const float* in_w = (const float*)d_in[6];
  const float* in_b = (const float*)d_in[7];
  const float* q_w  = (const float*)d_in[8];
  const float* q_b  = (const float*)d_in[9];
  const float* k_w  = (const float*)d_in[10];
  const float* k_b  = (const float*)d_in[11];
  const float* v_w  = (const float*)d_in[12];
  const float* v_b  = (const float*)d_in[13];
  const float* w1   = (const float*)d_in[14];
  const float* b1   = (const float*)d_in[15];
  const float* w2   = (const float*)d_in[16];
  const float* b2   = (const float*)d_in[17];

  // full (1 chunk, ~295 MiB) if it fits, else 2-chunk (~199 MiB).
  const size_t FULL_BYTES = 309198848ull;
  int nchunks = (ws_size >= FULL_BYTES) ? 1 : 2;
  int nnz = 512 / nchunks;                 // sequences per chunk
  size_t qkvsz = (size_t)nnz * 65536 * 2;  // bytes per Q/K/V buffer

  char* ws = (char*)d_ws;
  size_t off = 0;
  unsigned short* tem  = (unsigned short*)(ws + off); off += 4194304;
  float*          cur  = (float*)(ws + off);          off += 67108864;
  unsigned short* enc  = (unsigned short*)(ws + off); off += 33554432;
  unsigned short* qb   = (unsigned short*)(ws + off); off += qkvsz;
  unsigned short* kb   = (unsigned short*)(ws + off); off += qkvsz;
  unsigned short* vtb  = (unsigned short*)(ws + off); off += qkvsz;
  float*          feat = (float*)(ws + off);          off += 1048576;
  unsigned short* wT   = (unsigned short*)(ws + off); off += 1966080;
  float* out = (float*)d_out;

  k_wprep<<<3840, 256, 0, stream>>>(in_w, q_w, k_w, v_w, wT);
  k_temporal<<<4096, 256, 0, stream>>>(tim, (unsigned int*)tem);
  k_inproj<<<1024, 256, 0, stream>>>(subj, obj, rel, ent, rele, wT, in_b, enc);

  for (int h = 0; h < 2; h++){
    for (int l = 0; l < 2; l++){
      int o = h * 2 + l;
      int lzero = (l == 0) ? 1 : 0;
      int hsel = (l == 1) ? h : -1;
      const unsigned short* wq = wT + 98304 + (size_t)(o * 3 + 0) * 73728;
      const unsigned short* wk = wT + 98304 + (size_t)(o * 3 + 1) * 73728;
      const unsigned short* wv = wT + 98304 + (size_t)(o * 3 + 2) * 73728;
      for (int c = 0; c < nchunks; c++){
        k_qkv<<<nnz * 8, 256, 0, stream>>>(enc, cur, tem, wq, wk, wv,
            q_b + o * 256, k_b + o * 256, v_b + o * 256, c * nnz, lzero,
            qb, kb, vtb);
        k_attn<<<nnz * 2, 256, 0, stream>>>(qb, kb, vtb, enc, cur, tim,
            c * nnz, lzero, hsel, feat);
      }
    }
  }
  k_mlp<<<512, 256, 0, stream>>>(feat, w1, b1, w2, b2, out);
}